// Round 8
// baseline (216.112 us; speedup 1.0000x reference)
//
#include <hip/hip_runtime.h>
#include <hip/hip_bf16.h>

#define HW_  9216        // 96*96
#define CHW_ 2359296     // 256*9216

typedef __attribute__((ext_vector_type(8))) short bf16x8;
typedef __attribute__((ext_vector_type(4))) float f32x4;

__device__ __forceinline__ short f2bf(float f) {
  union { float f; unsigned u; } v; v.f = f;
  unsigned r = v.u + 0x7fff + ((v.u >> 16) & 1);   // RNE, no NaNs in this data
  return (short)(r >> 16);
}
__device__ __forceinline__ float bflo(unsigned u) {
  union { unsigned u; float f; } v; v.u = u << 16; return v.f;
}
__device__ __forceinline__ float bfhi(unsigned u) {
  union { unsigned u; float f; } v; v.u = u & 0xffff0000u; return v.f;
}

// bilinear combine of 4 packed-bf16 corners (8 channels) -> bf16 A-fragment
__device__ __forceinline__ bf16x8 combine4(const uint4 g0, const uint4 g1,
                                           const uint4 g2, const uint4 g3,
                                           const float4 w) {
  bf16x8 r;
#define CMB(gw0, gw1, gw2, gw3, e)                                              \
  r[e]     = f2bf(w.x * bflo(gw0) + w.y * bflo(gw1) + w.z * bflo(gw2) + w.w * bflo(gw3)); \
  r[(e)+1] = f2bf(w.x * bfhi(gw0) + w.y * bfhi(gw1) + w.z * bfhi(gw2) + w.w * bfhi(gw3));
  CMB(g0.x, g1.x, g2.x, g3.x, 0)
  CMB(g0.y, g1.y, g2.y, g3.y, 2)
  CMB(g0.z, g1.z, g2.z, g3.z, 4)
  CMB(g0.w, g1.w, g2.w, g3.w, 6)
#undef CMB
  return r;
}

// ---------------- x: NCHW f32 -> NHWC bf16 ----------------
__global__ void k_transpose2(const float* __restrict__ x, short* __restrict__ xt) {
  __shared__ float tile[32][33];
  const int b = blockIdx.z;
  const int hw0 = blockIdx.x * 32;
  const int c0 = blockIdx.y * 32;
  const int tx = threadIdx.x, ty = threadIdx.y;   // 32 x 8
  const float* xb = x + (size_t)b * CHW_;
  short* xtb = xt + (size_t)b * CHW_;
#pragma unroll
  for (int s = 0; s < 4; ++s)
    tile[ty + s * 8][tx] = xb[(size_t)(c0 + ty + s * 8) * HW_ + hw0 + tx];
  __syncthreads();
  const int tid = ty * 32 + tx;
  const int cp = tid & 15;    // channel pair
  const int hh = tid >> 4;    // 0..15
#pragma unroll
  for (int s = 0; s < 2; ++s) {
    const int hw = hh + s * 16;
    short2 v;
    v.x = f2bf(tile[2 * cp][hw]);
    v.y = f2bf(tile[2 * cp + 1][hw]);
    *(short2*)&xtb[(size_t)(hw0 + hw) * 256 + c0 + 2 * cp] = v;
  }
}

// ------- prep: deform_w + offset_w -> bf16 MFMA b-fragment layouts -------
__global__ void k_prep(const float* __restrict__ dw, const float* __restrict__ ow,
                       short* __restrict__ wfrag, short* __restrict__ owfrag) {
  const int idx = blockIdx.x * 256 + threadIdx.x;
  if (idx < 589824) {
    const int i = idx & 7, l = (idx >> 3) & 63, nf = (idx >> 9) & 15, kb = idx >> 13;
    const int o = nf * 16 + (l & 15);
    const int c = (kb & 7) * 32 + (l >> 4) * 8 + i;
    const int kk = kb >> 3;
    wfrag[idx] = f2bf(dw[(size_t)(o * 256 + c) * 9 + kk]);
  } else {
    const int j = idx - 589824;   // < 73728
    const int i = j & 7, l = (j >> 3) & 63, nf = (j >> 9) & 1, s = j >> 10;
    const int o = nf * 16 + (l & 15);
    const int c = ((s & 7) << 5) + ((l >> 4) << 3) + i;
    const int kk = s >> 3;
    owfrag[j] = (o < 18) ? f2bf(ow[(size_t)(o * 256 + c) * 9 + kk]) : (short)0;
  }
}

// ---- fused: offset conv (A) + metadata (B) + barrier-free K-split GEMM (C) ----
// 1152 blocks x 128 threads (2 waves). Block = 1 ho row x 32 wo, all 256 outs.
// Wave w computes K-half [w*36, w*36+36) for all 32 px x 256 outs.
// A-fragments gathered per-lane into registers (no LDS, no barriers in loop);
// B-fragments stream from L2 in 4-frag groups. Epilogue: LDS reduce of halves.
__global__ __launch_bounds__(128) void k_deform(
    const short* __restrict__ xt, const short* __restrict__ wfrag,
    const short* __restrict__ owfrag, const float* __restrict__ ob,
    const float* __restrict__ db, float* __restrict__ out) {
  __shared__ __align__(16) char smem[16384];
  float*  offsLDS = (float*)smem;            // [32][32] f32 (phase A out)
  float4* mwP = (float4*)(smem + 4096);      // [288] bilinear weights
  short4* miP = (short4*)(smem + 8704);      // [288] corner pixel indices
  f32x4*  epi = (f32x4*)smem;                // [16][64] epilogue overlay

  const int tid = threadIdx.x;
  // XCD-aware bijective swizzle: 1152 = 8 XCDs x 144 contiguous strips
  const int blk0 = blockIdx.x;
  const int blk = (blk0 & 7) * 144 + (blk0 >> 3);
  const int b = blk / 288;
  const int r = blk % 288;
  const int ho0 = r / 3;
  const int wo0 = (r % 3) * 32;
  const short* xb = xt + (size_t)b * CHW_;
  const int lane = tid & 63;
  const int wave = tid >> 6;   // 0..1

  // ---- phase A: offset conv, wave w -> pixels w*16..w*16+15, outs 0..31 ----
  {
    const int pA = wave * 16 + (lane & 15);
    const int woA = wo0 + pA;
    const int coff = (lane >> 4) << 3;
    f32x4 oa0 = {0.f, 0.f, 0.f, 0.f}, oa1 = {0.f, 0.f, 0.f, 0.f};
#pragma unroll 4
    for (int s = 0; s < 72; ++s) {
      const int kk = s >> 3;
      const int c0 = (s & 7) << 5;
      const int y = ho0 - 1 + kk / 3;
      const int x = woA - 1 + kk % 3;
      bf16x8 af = {0, 0, 0, 0, 0, 0, 0, 0};
      if ((unsigned)y < 96u && (unsigned)x < 96u)
        af = *(const bf16x8*)(xb + ((y * 96 + x) << 8) + c0 + coff);
      const bf16x8 b0 = *(const bf16x8*)(owfrag + (size_t)s * 1024 + lane * 8);
      const bf16x8 b1 = *(const bf16x8*)(owfrag + (size_t)s * 1024 + 512 + lane * 8);
      oa0 = __builtin_amdgcn_mfma_f32_16x16x32_bf16(af, b0, oa0, 0, 0, 0);
      oa1 = __builtin_amdgcn_mfma_f32_16x16x32_bf16(af, b1, oa1, 0, 0, 0);
    }
    const int r0 = wave * 16 + (lane >> 4) * 4;
    const int cc = lane & 15;
#pragma unroll
    for (int j = 0; j < 4; ++j) {
      offsLDS[(r0 + j) * 32 + cc] = oa0[j];
      offsLDS[(r0 + j) * 32 + 16 + cc] = oa1[j];
    }
  }
  // no barrier: each wave consumes only its own pixels' offsets below

  // ---- phase B: metadata for own 16 pixels x 9 kk ----
  for (int e2 = lane; e2 < 144; e2 += 64) {
    const int kk = e2 >> 4;
    const int p = wave * 16 + (e2 & 15);
    const int wo = wo0 + p;
    const float dy = offsLDS[p * 32 + 2 * kk] + ob[2 * kk];
    const float dx = offsLDS[p * 32 + 2 * kk + 1] + ob[2 * kk + 1];
    const float pyf = (float)(ho0 - 1 + kk / 3) + dy;
    const float pxf = (float)(wo - 1 + kk % 3) + dx;
    const float y0f = floorf(pyf), x0f = floorf(pxf);
    const float ty = pyf - y0f, tx = pxf - x0f;
    const int y0 = (int)y0f, x0 = (int)x0f;
    const int y1 = y0 + 1, x1 = x0 + 1;
    const float vy0 = ((unsigned)y0 < 96u) ? 1.f : 0.f;
    const float vy1 = ((unsigned)y1 < 96u) ? 1.f : 0.f;
    const float vx0 = ((unsigned)x0 < 96u) ? 1.f : 0.f;
    const float vx1 = ((unsigned)x1 < 96u) ? 1.f : 0.f;
    const float oy = 1.f - ty, ox = 1.f - tx;
    float4 w4;
    w4.x = oy * ox * vy0 * vx0;
    w4.y = oy * tx * vy0 * vx1;
    w4.z = ty * ox * vy1 * vx0;
    w4.w = ty * tx * vy1 * vx1;
    const int cy0 = min(max(y0, 0), 95), cy1 = min(max(y1, 0), 95);
    const int cx0 = min(max(x0, 0), 95), cx1 = min(max(x1, 0), 95);
    const int u = kk * 32 + p;
    mwP[u] = w4;
    miP[u] = make_short4((short)(cy0 * 96 + cx0), (short)(cy0 * 96 + cx1),
                         (short)(cy1 * 96 + cx0), (short)(cy1 * 96 + cx1));
  }
  __syncthreads();   // the only pre-loop barrier (cross-wave metadata)

  // ---- phase C: barrier-free K-half GEMM ----
  const int p0 = lane & 15;
  const int kc8 = (lane >> 4) << 3;

  f32x4 acc[2][16];
#pragma unroll
  for (int m = 0; m < 2; ++m)
#pragma unroll
    for (int j = 0; j < 16; ++j) acc[m][j] = (f32x4){0.f, 0.f, 0.f, 0.f};

  int kb = wave * 36;
  // metadata + first corners
  float4 w40, w41;
  int4 a40, a41;
  {
    const int kk = kb >> 3;
    const int u0 = kk * 32 + p0;
    const int u1 = u0 + 16;
    w40 = mwP[u0]; w41 = mwP[u1];
    const short4 m0 = miP[u0], m1 = miP[u1];
    a40.x = ((int)m0.x) << 8; a40.y = ((int)m0.y) << 8;
    a40.z = ((int)m0.z) << 8; a40.w = ((int)m0.w) << 8;
    a41.x = ((int)m1.x) << 8; a41.y = ((int)m1.y) << 8;
    a41.z = ((int)m1.z) << 8; a41.w = ((int)m1.w) << 8;
  }
  const int cb0 = ((kb & 7) << 5) + kc8;
  uint4 GA0 = *(const uint4*)(xb + a40.x + cb0);
  uint4 GA1 = *(const uint4*)(xb + a40.y + cb0);
  uint4 GA2 = *(const uint4*)(xb + a40.z + cb0);
  uint4 GA3 = *(const uint4*)(xb + a40.w + cb0);
  uint4 GB0 = *(const uint4*)(xb + a41.x + cb0);
  uint4 GB1 = *(const uint4*)(xb + a41.y + cb0);
  uint4 GB2 = *(const uint4*)(xb + a41.z + cb0);
  uint4 GB3 = *(const uint4*)(xb + a41.w + cb0);

  for (int st = 0; st < 36; ++st, ++kb) {
    const short* wb = wfrag + ((size_t)(kb * 16) * 64 + lane) * 8;
    // B group 0 issued before combine (combine VALU covers L2 latency)
    bf16x8 f0 = *(const bf16x8*)(wb);
    bf16x8 f1 = *(const bf16x8*)(wb + 512);
    bf16x8 f2 = *(const bf16x8*)(wb + 1024);
    bf16x8 f3 = *(const bf16x8*)(wb + 1536);
    const bf16x8 af0 = combine4(GA0, GA1, GA2, GA3, w40);
    const bf16x8 af1 = combine4(GB0, GB1, GB2, GB3, w41);
    // prefetch next step's corners (latency covered by MFMAs below)
    if (st < 35) {
      const int kbn = kb + 1;
      if ((kbn & 7) == 0) {
        const int kkn = kbn >> 3;
        const int u0 = kkn * 32 + p0;
        const int u1 = u0 + 16;
        w40 = mwP[u0]; w41 = mwP[u1];
        const short4 m0 = miP[u0], m1 = miP[u1];
        a40.x = ((int)m0.x) << 8; a40.y = ((int)m0.y) << 8;
        a40.z = ((int)m0.z) << 8; a40.w = ((int)m0.w) << 8;
        a41.x = ((int)m1.x) << 8; a41.y = ((int)m1.y) << 8;
        a41.z = ((int)m1.z) << 8; a41.w = ((int)m1.w) << 8;
      }
      const int cbn = ((kbn & 7) << 5) + kc8;
      GA0 = *(const uint4*)(xb + a40.x + cbn);
      GA1 = *(const uint4*)(xb + a40.y + cbn);
      GA2 = *(const uint4*)(xb + a40.z + cbn);
      GA3 = *(const uint4*)(xb + a40.w + cbn);
      GB0 = *(const uint4*)(xb + a41.x + cbn);
      GB1 = *(const uint4*)(xb + a41.y + cbn);
      GB2 = *(const uint4*)(xb + a41.z + cbn);
      GB3 = *(const uint4*)(xb + a41.w + cbn);
    }
    // B group 1 + MFMAs on group 0
    bf16x8 f4 = *(const bf16x8*)(wb + 2048);
    bf16x8 f5 = *(const bf16x8*)(wb + 2560);
    bf16x8 f6 = *(const bf16x8*)(wb + 3072);
    bf16x8 f7 = *(const bf16x8*)(wb + 3584);
    acc[0][0] = __builtin_amdgcn_mfma_f32_16x16x32_bf16(af0, f0, acc[0][0], 0, 0, 0);
    acc[1][0] = __builtin_amdgcn_mfma_f32_16x16x32_bf16(af1, f0, acc[1][0], 0, 0, 0);
    acc[0][1] = __builtin_amdgcn_mfma_f32_16x16x32_bf16(af0, f1, acc[0][1], 0, 0, 0);
    acc[1][1] = __builtin_amdgcn_mfma_f32_16x16x32_bf16(af1, f1, acc[1][1], 0, 0, 0);
    acc[0][2] = __builtin_amdgcn_mfma_f32_16x16x32_bf16(af0, f2, acc[0][2], 0, 0, 0);
    acc[1][2] = __builtin_amdgcn_mfma_f32_16x16x32_bf16(af1, f2, acc[1][2], 0, 0, 0);
    acc[0][3] = __builtin_amdgcn_mfma_f32_16x16x32_bf16(af0, f3, acc[0][3], 0, 0, 0);
    acc[1][3] = __builtin_amdgcn_mfma_f32_16x16x32_bf16(af1, f3, acc[1][3], 0, 0, 0);
    // B group 2 + MFMAs on group 1
    bf16x8 f8  = *(const bf16x8*)(wb + 4096);
    bf16x8 f9  = *(const bf16x8*)(wb + 4608);
    bf16x8 f10 = *(const bf16x8*)(wb + 5120);
    bf16x8 f11 = *(const bf16x8*)(wb + 5632);
    acc[0][4] = __builtin_amdgcn_mfma_f32_16x16x32_bf16(af0, f4, acc[0][4], 0, 0, 0);
    acc[1][4] = __builtin_amdgcn_mfma_f32_16x16x32_bf16(af1, f4, acc[1][4], 0, 0, 0);
    acc[0][5] = __builtin_amdgcn_mfma_f32_16x16x32_bf16(af0, f5, acc[0][5], 0, 0, 0);
    acc[1][5] = __builtin_amdgcn_mfma_f32_16x16x32_bf16(af1, f5, acc[1][5], 0, 0, 0);
    acc[0][6] = __builtin_amdgcn_mfma_f32_16x16x32_bf16(af0, f6, acc[0][6], 0, 0, 0);
    acc[1][6] = __builtin_amdgcn_mfma_f32_16x16x32_bf16(af1, f6, acc[1][6], 0, 0, 0);
    acc[0][7] = __builtin_amdgcn_mfma_f32_16x16x32_bf16(af0, f7, acc[0][7], 0, 0, 0);
    acc[1][7] = __builtin_amdgcn_mfma_f32_16x16x32_bf16(af1, f7, acc[1][7], 0, 0, 0);
    // B group 3 + MFMAs on group 2
    bf16x8 f12 = *(const bf16x8*)(wb + 6144);
    bf16x8 f13 = *(const bf16x8*)(wb + 6656);
    bf16x8 f14 = *(const bf16x8*)(wb + 7168);
    bf16x8 f15 = *(const bf16x8*)(wb + 7680);
    acc[0][8]  = __builtin_amdgcn_mfma_f32_16x16x32_bf16(af0, f8,  acc[0][8],  0, 0, 0);
    acc[1][8]  = __builtin_amdgcn_mfma_f32_16x16x32_bf16(af1, f8,  acc[1][8],  0, 0, 0);
    acc[0][9]  = __builtin_amdgcn_mfma_f32_16x16x32_bf16(af0, f9,  acc[0][9],  0, 0, 0);
    acc[1][9]  = __builtin_amdgcn_mfma_f32_16x16x32_bf16(af1, f9,  acc[1][9],  0, 0, 0);
    acc[0][10] = __builtin_amdgcn_mfma_f32_16x16x32_bf16(af0, f10, acc[0][10], 0, 0, 0);
    acc[1][10] = __builtin_amdgcn_mfma_f32_16x16x32_bf16(af1, f10, acc[1][10], 0, 0, 0);
    acc[0][11] = __builtin_amdgcn_mfma_f32_16x16x32_bf16(af0, f11, acc[0][11], 0, 0, 0);
    acc[1][11] = __builtin_amdgcn_mfma_f32_16x16x32_bf16(af1, f11, acc[1][11], 0, 0, 0);
    acc[0][12] = __builtin_amdgcn_mfma_f32_16x16x32_bf16(af0, f12, acc[0][12], 0, 0, 0);
    acc[1][12] = __builtin_amdgcn_mfma_f32_16x16x32_bf16(af1, f12, acc[1][12], 0, 0, 0);
    acc[0][13] = __builtin_amdgcn_mfma_f32_16x16x32_bf16(af0, f13, acc[0][13], 0, 0, 0);
    acc[1][13] = __builtin_amdgcn_mfma_f32_16x16x32_bf16(af1, f13, acc[1][13], 0, 0, 0);
    acc[0][14] = __builtin_amdgcn_mfma_f32_16x16x32_bf16(af0, f14, acc[0][14], 0, 0, 0);
    acc[1][14] = __builtin_amdgcn_mfma_f32_16x16x32_bf16(af1, f14, acc[1][14], 0, 0, 0);
    acc[0][15] = __builtin_amdgcn_mfma_f32_16x16x32_bf16(af0, f15, acc[0][15], 0, 0, 0);
    acc[1][15] = __builtin_amdgcn_mfma_f32_16x16x32_bf16(af1, f15, acc[1][15], 0, 0, 0);
  }

  // ---- epilogue: reduce the two K-halves via LDS, wave0 stores ----
  const int col = lane & 15;
  const int rg = lane >> 4;
#pragma unroll
  for (int h = 0; h < 2; ++h) {
    if (wave == 1) {
#pragma unroll
      for (int j = 0; j < 16; ++j) epi[j * 64 + lane] = acc[h][j];
    }
    __syncthreads();
    if (wave == 0) {
      const int pixbase = ho0 * 96 + wo0 + h * 16 + rg * 4;
#pragma unroll
      for (int j = 0; j < 16; ++j) {
        const f32x4 vv = epi[j * 64 + lane];
        const int o = j * 16 + col;
        const float bv = db[o];
        float4 v;
        v.x = acc[h][j][0] + vv[0] + bv;
        v.y = acc[h][j][1] + vv[1] + bv;
        v.z = acc[h][j][2] + vv[2] + bv;
        v.w = acc[h][j][3] + vv[3] + bv;
        *(float4*)(out + (size_t)(b * 256 + o) * HW_ + pixbase) = v;
      }
    }
    __syncthreads();
  }
}

extern "C" void kernel_launch(void* const* d_in, const int* in_sizes, int n_in,
                              void* d_out, int out_size, void* d_ws, size_t ws_size,
                              hipStream_t stream) {
  const float* x  = (const float*)d_in[0];
  const float* ow = (const float*)d_in[1];
  const float* ob = (const float*)d_in[2];
  const float* dw = (const float*)d_in[3];
  const float* db = (const float*)d_in[4];
  float* out = (float*)d_out;
  float* ws = (float*)d_ws;

  short* xt     = (short*)ws;                // 9,437,184 bf16 (18.9 MB)
  short* wfrag  = (short*)(ws + 4718592);    //   589,824 bf16
  short* owfrag = wfrag + 589824;            //    73,728 bf16  (~20.2 MB total)

  hipLaunchKernelGGL(k_transpose2, dim3(288, 8, 4), dim3(32, 8, 1), 0, stream, x, xt);
  hipLaunchKernelGGL(k_prep, dim3(2592), dim3(256), 0, stream, dw, ow, wfrag, owfrag);
  hipLaunchKernelGGL(k_deform, dim3(1152), dim3(128), 0, stream,
                     xt, wfrag, owfrag, ob, db, out);
}

// Round 9
// 130.312 us; speedup vs baseline: 1.6584x; 1.6584x over previous
//
#include <hip/hip_runtime.h>
#include <hip/hip_bf16.h>

#define HW_  9216        // 96*96
#define CHW_ 2359296     // 256*9216

typedef __attribute__((ext_vector_type(8))) short bf16x8;
typedef __attribute__((ext_vector_type(4))) float f32x4;

__device__ __forceinline__ short f2bf(float f) {
  union { float f; unsigned u; } v; v.f = f;
  unsigned r = v.u + 0x7fff + ((v.u >> 16) & 1);   // RNE, no NaNs in this data
  return (short)(r >> 16);
}
__device__ __forceinline__ float bflo(unsigned u) {
  union { unsigned u; float f; } v; v.u = u << 16; return v.f;
}
__device__ __forceinline__ float bfhi(unsigned u) {
  union { unsigned u; float f; } v; v.u = u & 0xffff0000u; return v.f;
}

// bilinear combine of 4 packed-bf16 corners (8 channels) -> bf16 A-fragment
__device__ __forceinline__ bf16x8 combine4(const uint4 g0, const uint4 g1,
                                           const uint4 g2, const uint4 g3,
                                           const float4 w) {
  bf16x8 r;
#define CMB(gw0, gw1, gw2, gw3, e)                                              \
  r[e]     = f2bf(w.x * bflo(gw0) + w.y * bflo(gw1) + w.z * bflo(gw2) + w.w * bflo(gw3)); \
  r[(e)+1] = f2bf(w.x * bfhi(gw0) + w.y * bfhi(gw1) + w.z * bfhi(gw2) + w.w * bfhi(gw3));
  CMB(g0.x, g1.x, g2.x, g3.x, 0)
  CMB(g0.y, g1.y, g2.y, g3.y, 2)
  CMB(g0.z, g1.z, g2.z, g3.z, 4)
  CMB(g0.w, g1.w, g2.w, g3.w, 6)
#undef CMB
  return r;
}

// ---------------- x: NCHW f32 -> NHWC bf16 ----------------
__global__ void k_transpose2(const float* __restrict__ x, short* __restrict__ xt) {
  __shared__ float tile[32][33];
  const int b = blockIdx.z;
  const int hw0 = blockIdx.x * 32;
  const int c0 = blockIdx.y * 32;
  const int tx = threadIdx.x, ty = threadIdx.y;   // 32 x 8
  const float* xb = x + (size_t)b * CHW_;
  short* xtb = xt + (size_t)b * CHW_;
#pragma unroll
  for (int s = 0; s < 4; ++s)
    tile[ty + s * 8][tx] = xb[(size_t)(c0 + ty + s * 8) * HW_ + hw0 + tx];
  __syncthreads();
  const int tid = ty * 32 + tx;
  const int cp = tid & 15;    // channel pair
  const int hh = tid >> 4;    // 0..15
#pragma unroll
  for (int s = 0; s < 2; ++s) {
    const int hw = hh + s * 16;
    short2 v;
    v.x = f2bf(tile[2 * cp][hw]);
    v.y = f2bf(tile[2 * cp + 1][hw]);
    *(short2*)&xtb[(size_t)(hw0 + hw) * 256 + c0 + 2 * cp] = v;
  }
}

// ------- prep: deform_w + offset_w -> bf16 MFMA b-fragment layouts -------
__global__ void k_prep(const float* __restrict__ dw, const float* __restrict__ ow,
                       short* __restrict__ wfrag, short* __restrict__ owfrag) {
  const int idx = blockIdx.x * 256 + threadIdx.x;
  if (idx < 589824) {
    const int i = idx & 7, l = (idx >> 3) & 63, nf = (idx >> 9) & 15, kb = idx >> 13;
    const int o = nf * 16 + (l & 15);
    const int c = (kb & 7) * 32 + (l >> 4) * 8 + i;
    const int kk = kb >> 3;
    wfrag[idx] = f2bf(dw[(size_t)(o * 256 + c) * 9 + kk]);
  } else {
    const int j = idx - 589824;   // < 73728
    const int i = j & 7, l = (j >> 3) & 63, nf = (j >> 9) & 1, s = j >> 10;
    const int o = nf * 16 + (l & 15);
    const int c = ((s & 7) << 5) + ((l >> 4) << 3) + i;
    const int kk = s >> 3;
    owfrag[j] = (o < 18) ? f2bf(ow[(size_t)(o * 256 + c) * 9 + kk]) : (short)0;
  }
}

// ---- fused: offset conv (A) + metadata (B) + deform GEMM (C, K-step=64) ----
// 1152 blocks x 128 threads (2 waves). Block = 1 ho row x 32 wo, all 256 outs.
// Phase C: waves split N (wave w: 32 px x outputs [w*128, w*128+128)).
// A staged in LDS (64 ch / step, double-buffered, 1 barrier/step);
// staging metadata register-resident, refreshed every 4th step.
__global__ __launch_bounds__(128) void k_deform(
    const short* __restrict__ xt, const short* __restrict__ wfrag,
    const short* __restrict__ owfrag, const float* __restrict__ ob,
    const float* __restrict__ db, float* __restrict__ out) {
  __shared__ __align__(16) char smem[25344];
  short*  vals = (short*)smem;               // 2 x [32][72] bf16 (dbuf, 64ch+pad)
  float*  offsLDS = (float*)smem;            // [32][32] f32 overlay (phase A out)
  float4* mwP = (float4*)(smem + 18432);     // [288]
  short4* miP = (short4*)(smem + 23040);     // [288]

  const int tid = threadIdx.x;
  // XCD-aware bijective swizzle: 1152 = 8 XCDs x 144 contiguous strips
  const int blk0 = blockIdx.x;
  const int blk = (blk0 & 7) * 144 + (blk0 >> 3);
  const int b = blk / 288;
  const int r = blk % 288;
  const int ho0 = r / 3;
  const int wo0 = (r % 3) * 32;
  const short* xb = xt + (size_t)b * CHW_;
  const int lane = tid & 63;
  const int wave = tid >> 6;   // 0..1

  // ---- phase A: offset conv for this block's 32 pixels (register MFMA) ----
  {
    const int pA = wave * 16 + (lane & 15);
    const int woA = wo0 + pA;
    const int coff = (lane >> 4) << 3;
    f32x4 oa0 = {0.f, 0.f, 0.f, 0.f}, oa1 = {0.f, 0.f, 0.f, 0.f};
#pragma unroll 4
    for (int s = 0; s < 72; ++s) {
      const int kk = s >> 3;
      const int c0 = (s & 7) << 5;
      const int y = ho0 - 1 + kk / 3;
      const int x = woA - 1 + kk % 3;
      bf16x8 af = {0, 0, 0, 0, 0, 0, 0, 0};
      if ((unsigned)y < 96u && (unsigned)x < 96u)
        af = *(const bf16x8*)(xb + ((y * 96 + x) << 8) + c0 + coff);
      const bf16x8 b0 = *(const bf16x8*)(owfrag + (size_t)s * 1024 + lane * 8);
      const bf16x8 b1 = *(const bf16x8*)(owfrag + (size_t)s * 1024 + 512 + lane * 8);
      oa0 = __builtin_amdgcn_mfma_f32_16x16x32_bf16(af, b0, oa0, 0, 0, 0);
      oa1 = __builtin_amdgcn_mfma_f32_16x16x32_bf16(af, b1, oa1, 0, 0, 0);
    }
    const int r0 = wave * 16 + (lane >> 4) * 4;
    const int cc = lane & 15;
#pragma unroll
    for (int j = 0; j < 4; ++j) {
      offsLDS[(r0 + j) * 32 + cc] = oa0[j];
      offsLDS[(r0 + j) * 32 + 16 + cc] = oa1[j];
    }
  }
  __syncthreads();

  // ---- phase B: sampling metadata: 9 kk x 32 pixels ----
  for (int u = tid; u < 288; u += 128) {
    const int kk = u >> 5;
    const int p = u & 31;
    const int wo = wo0 + p;
    const float dy = offsLDS[p * 32 + 2 * kk] + ob[2 * kk];
    const float dx = offsLDS[p * 32 + 2 * kk + 1] + ob[2 * kk + 1];
    const float py = (float)(ho0 - 1 + kk / 3) + dy;
    const float px = (float)(wo - 1 + kk % 3) + dx;
    const float y0f = floorf(py), x0f = floorf(px);
    const float ty = py - y0f, tx = px - x0f;
    const int y0 = (int)y0f, x0 = (int)x0f;
    const int y1 = y0 + 1, x1 = x0 + 1;
    const float vy0 = ((unsigned)y0 < 96u) ? 1.f : 0.f;
    const float vy1 = ((unsigned)y1 < 96u) ? 1.f : 0.f;
    const float vx0 = ((unsigned)x0 < 96u) ? 1.f : 0.f;
    const float vx1 = ((unsigned)x1 < 96u) ? 1.f : 0.f;
    const float oy = 1.f - ty, ox = 1.f - tx;
    float4 w4;
    w4.x = oy * ox * vy0 * vx0;
    w4.y = oy * tx * vy0 * vx1;
    w4.z = ty * ox * vy1 * vx0;
    w4.w = ty * tx * vy1 * vx1;
    const int cy0 = min(max(y0, 0), 95), cy1 = min(max(y1, 0), 95);
    const int cx0 = min(max(x0, 0), 95), cx1 = min(max(x1, 0), 95);
    mwP[u] = w4;
    miP[u] = make_short4((short)(cy0 * 96 + cx0), (short)(cy0 * 96 + cx1),
                         (short)(cy1 * 96 + cx0), (short)(cy1 * 96 + cx1));
  }
  __syncthreads();

  // ---- phase C: K-step = 64 channels, double-buffered, 1 barrier/step ----
  const int px = tid >> 2;        // 0..31 (staging pixel)
  const int ch0 = (tid & 3) << 4; // 16-channel group base

  f32x4 acc[2][8];
#pragma unroll
  for (int m = 0; m < 2; ++m)
#pragma unroll
    for (int j = 0; j < 8; ++j) acc[m][j] = (f32x4){0.f, 0.f, 0.f, 0.f};

  // staging metadata registers (refreshed when sb % 4 == 0)
  float4 w4 = mwP[px];
  int4 a4;
  {
    const short4 m0 = miP[px];
    a4.x = ((int)m0.x) << 8; a4.y = ((int)m0.y) << 8;
    a4.z = ((int)m0.z) << 8; a4.w = ((int)m0.w) << 8;
  }

  // prologue: stage sb=0 (channels 0..63) into buf0
#pragma unroll
  for (int t = 0; t < 2; ++t) {
    const int cl = ch0 + t * 8;
    const uint4 g0 = *(const uint4*)(xb + a4.x + cl);
    const uint4 g1 = *(const uint4*)(xb + a4.y + cl);
    const uint4 g2 = *(const uint4*)(xb + a4.z + cl);
    const uint4 g3 = *(const uint4*)(xb + a4.w + cl);
    *(bf16x8*)(&vals[px * 72 + cl]) = combine4(g0, g1, g2, g3, w4);
  }
  __syncthreads();

  for (int sb = 0; sb < 36; ++sb) {
    const short* vcur = vals + (sb & 1) * 2304;
    short* vnxt = vals + ((sb & 1) ^ 1) * 2304;
    const int kb0 = 2 * sb;

    // B-fragments: 2 k-subs x 8 n-frags for this wave (L2, 16B/lane)
    bf16x8 bfr[2][8];
    {
      const size_t wb0 = ((size_t)(kb0 * 16 + wave * 8) * 64 + lane) * 8;
      const size_t wb1 = wb0 + (size_t)16 * 64 * 8;
#pragma unroll
      for (int j = 0; j < 8; ++j) bfr[0][j] = *(const bf16x8*)(wfrag + wb0 + (size_t)j * 512);
#pragma unroll
      for (int j = 0; j < 8; ++j) bfr[1][j] = *(const bf16x8*)(wfrag + wb1 + (size_t)j * 512);
    }

    // issue gathers for sb+1 early (covered by the 32 MFMAs below)
    uint4 G[2][4];
    float4 w4n = w4;
    int4 a4n = a4;
    if (sb < 35) {
      const int sbn = sb + 1;
      if ((sbn & 3) == 0) {
        const int kkn = sbn >> 2;
        w4n = mwP[kkn * 32 + px];
        const short4 mn = miP[kkn * 32 + px];
        a4n.x = ((int)mn.x) << 8; a4n.y = ((int)mn.y) << 8;
        a4n.z = ((int)mn.z) << 8; a4n.w = ((int)mn.w) << 8;
      }
      const int cb = ((sbn & 3) << 6) + ch0;
#pragma unroll
      for (int t = 0; t < 2; ++t) {
        const int cl = cb + t * 8;
        G[t][0] = *(const uint4*)(xb + a4n.x + cl);
        G[t][1] = *(const uint4*)(xb + a4n.y + cl);
        G[t][2] = *(const uint4*)(xb + a4n.z + cl);
        G[t][3] = *(const uint4*)(xb + a4n.w + cl);
      }
    }

    // MFMAs on current buffer: 2 k-subs x 2 m-frags x 8 n-frags
#pragma unroll
    for (int ks = 0; ks < 2; ++ks) {
#pragma unroll
      for (int mf = 0; mf < 2; ++mf) {
        const int row = mf * 16 + (lane & 15);
        const bf16x8 af = *(const bf16x8*)(&vcur[row * 72 + ks * 32 + ((lane >> 4) << 3)]);
#pragma unroll
        for (int j = 0; j < 8; ++j)
          acc[mf][j] = __builtin_amdgcn_mfma_f32_16x16x32_bf16(af, bfr[ks][j], acc[mf][j], 0, 0, 0);
      }
    }

    // combine + write next buffer
    if (sb < 35) {
      const int cb = (((sb + 1) & 3) << 6) + ch0;
#pragma unroll
      for (int t = 0; t < 2; ++t) {
        const int cl = cb + t * 8;
        *(bf16x8*)(&vnxt[px * 72 + ((cl) & 63)]) =
            combine4(G[t][0], G[t][1], G[t][2], G[t][3], w4n);
      }
      w4 = w4n; a4 = a4n;
    }
    __syncthreads();
  }

  // ---- epilogue: D regs = 4 consecutive pixels -> float4 stores ----
  const int col = lane & 15;
  const int rg = lane >> 4;
#pragma unroll
  for (int mf = 0; mf < 2; ++mf) {
    const int pix = mf * 16 + rg * 4;
#pragma unroll
    for (int j = 0; j < 8; ++j) {
      const int o = wave * 128 + j * 16 + col;
      const float bv = db[o];
      float4 v;
      v.x = acc[mf][j][0] + bv;
      v.y = acc[mf][j][1] + bv;
      v.z = acc[mf][j][2] + bv;
      v.w = acc[mf][j][3] + bv;
      *(float4*)(out + (size_t)(b * 256 + o) * HW_ + ho0 * 96 + wo0 + pix) = v;
    }
  }
}

extern "C" void kernel_launch(void* const* d_in, const int* in_sizes, int n_in,
                              void* d_out, int out_size, void* d_ws, size_t ws_size,
                              hipStream_t stream) {
  const float* x  = (const float*)d_in[0];
  const float* ow = (const float*)d_in[1];
  const float* ob = (const float*)d_in[2];
  const float* dw = (const float*)d_in[3];
  const float* db = (const float*)d_in[4];
  float* out = (float*)d_out;
  float* ws = (float*)d_ws;

  short* xt     = (short*)ws;                // 9,437,184 bf16 (18.9 MB)
  short* wfrag  = (short*)(ws + 4718592);    //   589,824 bf16
  short* owfrag = wfrag + 589824;            //    73,728 bf16  (~20.2 MB total)

  hipLaunchKernelGGL(k_transpose2, dim3(288, 8, 4), dim3(32, 8, 1), 0, stream, x, xt);
  hipLaunchKernelGGL(k_prep, dim3(2592), dim3(256), 0, stream, dw, ow, wfrag, owfrag);
  hipLaunchKernelGGL(k_deform, dim3(1152), dim3(128), 0, stream,
                     xt, wfrag, owfrag, ob, db, out);
}